// Round 4
// baseline (49.310 us; speedup 1.0000x reference)
//
#include <hip/hip_runtime.h>
#include <math.h>

#define EPS_F 1e-8f

typedef float vfloat4 __attribute__((ext_vector_type(4)));

// ---------------------------------------------------------------------------
// lam_prep: lam[t] = max(tanh(raw_lambd[t]), EPS)  (tiny, L2-resident table)
// ---------------------------------------------------------------------------
__global__ void lam_prep_kernel(const float* __restrict__ raw_lambd,
                                float* __restrict__ lam_ws, int S) {
    int t = blockIdx.x * blockDim.x + threadIdx.x;
    if (t < S) lam_ws[t] = fmaxf(tanhf(raw_lambd[t]), EPS_F);
}

// ---------------------------------------------------------------------------
// One 64-lane wave per batch row, S = 2048 = 8 passes x 256 steps.
// KEY CHANGE vs R2: passes are INDEPENDENT. For pass p, each element's value
// is computed as an affine function (A_t, P_t) of the pass-end boundary
// G_{(p+1)*256}:   G_t = A_t + P_t * Gb.   The per-pass 256-step composite
// (pA, pP) is also recorded. Since no pass depends on another, the compiler
// can hoist/pipeline all loads across the fully-unrolled 8 passes (the
// serial carry no longer gates the memory stream). After the passes, the
// carry is propagated with 8 scalar FMAs and outputs are fixed up + stored.
//
// Per pass (verified machinery from R1):
//   a_t = r + gamma(1-d)(1-lam)v_{t+1},  b_t = gamma(1-d)lam
//   lane-local backward compose over its 4 elems -> (A,P)
//   wave Kogge-Stone SUFFIX scan -> lane l holds composite over lanes l..63
//   pass composite = lane 0's scan result (broadcast)
//   per-element affine replay from the lane's incoming suffix (lanes l+1..63)
// ---------------------------------------------------------------------------
template <bool USE_WS>
__global__ __launch_bounds__(256) void glam_scan_kernel(
    const float* __restrict__ values,    // B x (S+1), S = 2048
    const float* __restrict__ rewards,   // B x S
    const float* __restrict__ dones,     // B x S
    const float* __restrict__ raw_gamma, // 1
    const float* __restrict__ raw_lambd, // S
    const float* __restrict__ lam_ws,    // S (valid iff USE_WS)
    float* __restrict__ out,             // B x S
    int B)
{
    constexpr int S  = 2048;
    constexpr int NP = 8;                // passes of 256 timesteps

    const int wave = (blockIdx.x * blockDim.x + threadIdx.x) >> 6;
    const int lane = threadIdx.x & 63;
    if (wave >= B) return;

    const float gamma = fmaxf(tanhf(raw_gamma[0]), EPS_F);

    const size_t vbase = (size_t)wave * (size_t)(S + 1);
    const size_t base  = (size_t)wave * (size_t)S;
    const int lo4 = 4 * lane;

    const float vS = values[vbase + S];  // bootstrap G at t = S

    float oA[NP][4], oP[NP][4];          // per-element affine (static idx)
    float pA[NP], pP[NP];                // per-pass composites

    #pragma unroll
    for (int p = 0; p < NP; ++p) {
        const int e0 = (p << 8) + lo4;

        // Coalesced float4 loads (16B inter-lane stride).
        const vfloat4 r4 = *reinterpret_cast<const vfloat4*>(rewards + base + e0);
        const vfloat4 d4 = *reinterpret_cast<const vfloat4*>(dones   + base + e0);

        float lamv[4];
        if (USE_WS) {
            const vfloat4 l4 = *reinterpret_cast<const vfloat4*>(lam_ws + e0);
            lamv[0] = l4.x; lamv[1] = l4.y; lamv[2] = l4.z; lamv[3] = l4.w;
        } else {
            #pragma unroll
            for (int j = 0; j < 4; ++j)
                lamv[j] = fmaxf(tanhf(raw_lambd[e0 + j]), EPS_F);
        }

        // values row is only 4B-aligned (stride S+1): scalar loads; the 4
        // unrolled instructions fully consume each line (MSHR merge).
        float v1[4];
        #pragma unroll
        for (int j = 0; j < 4; ++j) v1[j] = values[vbase + e0 + 1 + j];

        const float rr[4] = { r4.x, r4.y, r4.z, r4.w };
        const float dd[4] = { d4.x, d4.y, d4.z, d4.w };

        float a[4], bb[4];
        #pragma unroll
        for (int j = 0; j < 4; ++j) {
            const float c = gamma * (1.0f - dd[j]);
            a[j]  = fmaf(c * (1.0f - lamv[j]), v1[j], rr[j]);
            bb[j] = c * lamv[j];
        }

        // Lane-local backward composition over the 4 owned steps.
        float A = 0.0f, P = 1.0f;
        #pragma unroll
        for (int j = 3; j >= 0; --j) {
            A = fmaf(bb[j], A, a[j]);
            P *= bb[j];
        }

        // Wave Kogge-Stone SUFFIX scan: lane l -> composite over lanes l..63.
        #pragma unroll
        for (int d = 1; d < 64; d <<= 1) {
            float A2 = __shfl_down(A, d);
            float P2 = __shfl_down(P, d);
            const bool valid = (lane + d) < 64;
            A2 = valid ? A2 : 0.0f;      // identity beyond the wave
            P2 = valid ? P2 : 1.0f;
            A = fmaf(P, A2, A);
            P *= P2;
        }

        // Pass composite (covers the whole 256-step pass) from lane 0.
        pA[p] = __shfl(A, 0);
        pP[p] = __shfl(P, 0);

        // Incoming suffix for this lane = composite over lanes l+1..63.
        const float A1 = __shfl_down(A, 1);
        const float P1 = __shfl_down(P, 1);
        float Af = (lane == 63) ? 0.0f : A1;
        float Pf = (lane == 63) ? 1.0f : P1;

        // Per-element affine replay: G_t = oA + oP * Gb(pass end).
        #pragma unroll
        for (int j = 3; j >= 0; --j) {
            Af = fmaf(bb[j], Af, a[j]);
            Pf = bb[j] * Pf;
            oA[p][j] = Af;
            oP[p][j] = Pf;
        }
    }

    // Carry propagation (8 scalar FMAs) + fixup + coalesced nt stores.
    float Gb = vS;                       // boundary value at t = S
    #pragma unroll
    for (int p = NP - 1; p >= 0; --p) {
        vfloat4 o4;
        o4.x = fmaf(oP[p][0], Gb, oA[p][0]);
        o4.y = fmaf(oP[p][1], Gb, oA[p][1]);
        o4.z = fmaf(oP[p][2], Gb, oA[p][2]);
        o4.w = fmaf(oP[p][3], Gb, oA[p][3]);
        __builtin_nontemporal_store(o4,
            reinterpret_cast<vfloat4*>(out + base + (p << 8) + lo4));
        Gb = fmaf(pP[p], Gb, pA[p]);     // boundary at t = p*256
    }
}

// ---------------------------------------------------------------------------
// Generic fallback (any S): one thread per row, sequential backward scan.
// ---------------------------------------------------------------------------
__global__ void glam_naive_kernel(const float* __restrict__ values,
                                  const float* __restrict__ rewards,
                                  const float* __restrict__ dones,
                                  const float* __restrict__ raw_gamma,
                                  const float* __restrict__ raw_lambd,
                                  float* __restrict__ out, int B, int S) {
    int b = blockIdx.x * blockDim.x + threadIdx.x;
    if (b >= B) return;
    const float gamma = fmaxf(tanhf(raw_gamma[0]), EPS_F);
    const size_t vbase = (size_t)b * (size_t)(S + 1);
    const size_t base  = (size_t)b * (size_t)S;
    float G = values[vbase + S];
    for (int t = S - 1; t >= 0; --t) {
        const float lt = fmaxf(tanhf(raw_lambd[t]), EPS_F);
        const float c  = gamma * (1.0f - dones[base + t]);
        G = rewards[base + t] + c * ((1.0f - lt) * values[vbase + t + 1] + lt * G);
        out[base + t] = G;
    }
}

extern "C" void kernel_launch(void* const* d_in, const int* in_sizes, int n_in,
                              void* d_out, int out_size, void* d_ws, size_t ws_size,
                              hipStream_t stream) {
    const float* values    = (const float*)d_in[0];
    const float* rewards   = (const float*)d_in[1];
    const float* dones     = (const float*)d_in[2];
    const float* raw_gamma = (const float*)d_in[3];
    const float* raw_lambd = (const float*)d_in[4];
    float* out = (float*)d_out;

    const int S = in_sizes[4];            // raw_lambd has S elements
    const int B = in_sizes[1] / S;        // rewards is B*S

    if (S != 2048) {
        // Shape outside the tuned path: correctness fallback.
        glam_naive_kernel<<<(B + 255) / 256, 256, 0, stream>>>(
            values, rewards, dones, raw_gamma, raw_lambd, out, B, S);
        return;
    }

    const int total_threads = B * 64;     // one wave per row
    const int blocks = (total_threads + 255) / 256;

    const bool use_ws = (d_ws != nullptr) && (ws_size >= (size_t)S * sizeof(float));
    if (use_ws) {
        float* lam_ws = (float*)d_ws;
        lam_prep_kernel<<<(S + 255) / 256, 256, 0, stream>>>(raw_lambd, lam_ws, S);
        glam_scan_kernel<true><<<blocks, 256, 0, stream>>>(
            values, rewards, dones, raw_gamma, raw_lambd, lam_ws, out, B);
    } else {
        glam_scan_kernel<false><<<blocks, 256, 0, stream>>>(
            values, rewards, dones, raw_gamma, raw_lambd, nullptr, out, B);
    }
}

// Round 5
// 47.429 us; speedup vs baseline: 1.0397x; 1.0397x over previous
//
#include <hip/hip_runtime.h>
#include <math.h>

#define EPS_F 1e-8f

typedef float vfloat4 __attribute__((ext_vector_type(4)));
// 4-byte-aligned float4: lets clang emit global_load_dwordx4 at dword-aligned
// (not 16B-aligned) addresses — gfx9+ supports dword-aligned multi-dword VMEM.
typedef float uafloat4 __attribute__((ext_vector_type(4), aligned(4)));

// ---------------------------------------------------------------------------
// One 64-lane wave per batch row, S = 2048 = 8 independent passes x 256 steps.
// Pass p, lane l owns t = p*256 + 4l + j (j=0..3). Per pass: build affine
// (a,b), lane-local compose, wave Kogge-Stone SUFFIX scan, record per-element
// affine (oA,oP) w.r.t. the pass-end boundary and the per-pass composite
// (pA,pP). No pass depends on another -> loads pipeline freely. Afterwards
// the carry propagates through 8 scalar FMAs; outputs fixed up + nt-stored.
//
// Transaction diet vs R3:
//  - lam staged in LDS once per block (row-independent!): per-pass lam read
//    is ds_read_b128 (no TA/L2 transactions at all).
//  - values loaded as dword-aligned dwordx4 (17 trans/pass vs 64 scalar).
// ---------------------------------------------------------------------------
__global__ __launch_bounds__(256) void glam_scan_kernel(
    const float* __restrict__ values,    // B x (S+1), S = 2048
    const float* __restrict__ rewards,   // B x S
    const float* __restrict__ dones,     // B x S
    const float* __restrict__ raw_gamma, // 1
    const float* __restrict__ raw_lambd, // S
    float* __restrict__ out,             // B x S
    int B)
{
    constexpr int S  = 2048;
    constexpr int NP = 8;                // passes of 256 timesteps

    __shared__ float lam_lds[S];

    const int tid  = threadIdx.x;
    const int wave = (blockIdx.x * blockDim.x + tid) >> 6;
    const int lane = tid & 63;

    // ---- Stage lam into LDS (dense coalesced reads, tanh once per block) ----
    #pragma unroll
    for (int k = 0; k < S / 256; ++k) {
        const int t = (k << 8) + tid;
        lam_lds[t] = fmaxf(tanhf(raw_lambd[t]), EPS_F);
    }
    __syncthreads();

    if (wave >= B) return;

    const float gamma = fmaxf(tanhf(raw_gamma[0]), EPS_F);

    const size_t vbase = (size_t)wave * (size_t)(S + 1);
    const size_t base  = (size_t)wave * (size_t)S;
    const int lo4 = 4 * lane;

    const float vS = values[vbase + S];  // bootstrap G at t = S

    float oA[NP][4], oP[NP][4];          // per-element affine (static idx)
    float pA[NP], pP[NP];                // per-pass composites

    #pragma unroll
    for (int p = 0; p < NP; ++p) {
        const int e0 = (p << 8) + lo4;

        // Coalesced float4 loads (16B inter-lane stride).
        const vfloat4 r4 = *reinterpret_cast<const vfloat4*>(rewards + base + e0);
        const vfloat4 d4 = *reinterpret_cast<const vfloat4*>(dones   + base + e0);

        // lam from LDS (zero global transactions; dense 16B-stride b128).
        const vfloat4 l4 = *reinterpret_cast<const vfloat4*>(&lam_lds[e0]);
        const float lamv[4] = { l4.x, l4.y, l4.z, l4.w };

        // values: dword-aligned dwordx4 (row stride S+1 is odd -> never 16B
        // aligned; gfx950 supports dword-aligned multi-dword loads).
        const uafloat4 v4 = *reinterpret_cast<const uafloat4*>(values + vbase + e0 + 1);
        const float v1[4] = { v4.x, v4.y, v4.z, v4.w };

        const float rr[4] = { r4.x, r4.y, r4.z, r4.w };
        const float dd[4] = { d4.x, d4.y, d4.z, d4.w };

        float a[4], bb[4];
        #pragma unroll
        for (int j = 0; j < 4; ++j) {
            const float c = gamma * (1.0f - dd[j]);
            a[j]  = fmaf(c * (1.0f - lamv[j]), v1[j], rr[j]);
            bb[j] = c * lamv[j];
        }

        // Lane-local backward composition over the 4 owned steps.
        float A = 0.0f, P = 1.0f;
        #pragma unroll
        for (int j = 3; j >= 0; --j) {
            A = fmaf(bb[j], A, a[j]);
            P *= bb[j];
        }

        // Wave Kogge-Stone SUFFIX scan: lane l -> composite over lanes l..63.
        #pragma unroll
        for (int d = 1; d < 64; d <<= 1) {
            float A2 = __shfl_down(A, d);
            float P2 = __shfl_down(P, d);
            const bool valid = (lane + d) < 64;
            A2 = valid ? A2 : 0.0f;      // identity beyond the wave
            P2 = valid ? P2 : 1.0f;
            A = fmaf(P, A2, A);
            P *= P2;
        }

        // Pass composite (whole 256-step pass) from lane 0.
        pA[p] = __shfl(A, 0);
        pP[p] = __shfl(P, 0);

        // Incoming suffix for this lane = composite over lanes l+1..63.
        const float A1 = __shfl_down(A, 1);
        const float P1 = __shfl_down(P, 1);
        float Af = (lane == 63) ? 0.0f : A1;
        float Pf = (lane == 63) ? 1.0f : P1;

        // Per-element affine replay: G_t = oA + oP * Gb(pass end).
        #pragma unroll
        for (int j = 3; j >= 0; --j) {
            Af = fmaf(bb[j], Af, a[j]);
            Pf = bb[j] * Pf;
            oA[p][j] = Af;
            oP[p][j] = Pf;
        }
    }

    // Carry propagation (8 scalar FMAs) + fixup + coalesced nt stores.
    float Gb = vS;                       // boundary value at t = S
    #pragma unroll
    for (int p = NP - 1; p >= 0; --p) {
        vfloat4 o4;
        o4.x = fmaf(oP[p][0], Gb, oA[p][0]);
        o4.y = fmaf(oP[p][1], Gb, oA[p][1]);
        o4.z = fmaf(oP[p][2], Gb, oA[p][2]);
        o4.w = fmaf(oP[p][3], Gb, oA[p][3]);
        __builtin_nontemporal_store(o4,
            reinterpret_cast<vfloat4*>(out + base + (p << 8) + lo4));
        Gb = fmaf(pP[p], Gb, pA[p]);     // boundary at t = p*256
    }
}

// ---------------------------------------------------------------------------
// Generic fallback (any S): one thread per row, sequential backward scan.
// ---------------------------------------------------------------------------
__global__ void glam_naive_kernel(const float* __restrict__ values,
                                  const float* __restrict__ rewards,
                                  const float* __restrict__ dones,
                                  const float* __restrict__ raw_gamma,
                                  const float* __restrict__ raw_lambd,
                                  float* __restrict__ out, int B, int S) {
    int b = blockIdx.x * blockDim.x + threadIdx.x;
    if (b >= B) return;
    const float gamma = fmaxf(tanhf(raw_gamma[0]), EPS_F);
    const size_t vbase = (size_t)b * (size_t)(S + 1);
    const size_t base  = (size_t)b * (size_t)S;
    float G = values[vbase + S];
    for (int t = S - 1; t >= 0; --t) {
        const float lt = fmaxf(tanhf(raw_lambd[t]), EPS_F);
        const float c  = gamma * (1.0f - dones[base + t]);
        G = rewards[base + t] + c * ((1.0f - lt) * values[vbase + t + 1] + lt * G);
        out[base + t] = G;
    }
}

extern "C" void kernel_launch(void* const* d_in, const int* in_sizes, int n_in,
                              void* d_out, int out_size, void* d_ws, size_t ws_size,
                              hipStream_t stream) {
    const float* values    = (const float*)d_in[0];
    const float* rewards   = (const float*)d_in[1];
    const float* dones     = (const float*)d_in[2];
    const float* raw_gamma = (const float*)d_in[3];
    const float* raw_lambd = (const float*)d_in[4];
    float* out = (float*)d_out;

    const int S = in_sizes[4];            // raw_lambd has S elements
    const int B = in_sizes[1] / S;        // rewards is B*S

    if (S != 2048) {
        // Shape outside the tuned path: correctness fallback.
        glam_naive_kernel<<<(B + 255) / 256, 256, 0, stream>>>(
            values, rewards, dones, raw_gamma, raw_lambd, out, B, S);
        return;
    }

    const int total_threads = B * 64;     // one wave per row
    const int blocks = (total_threads + 255) / 256;

    glam_scan_kernel<<<blocks, 256, 0, stream>>>(
        values, rewards, dones, raw_gamma, raw_lambd, out, B);
}